// Round 7
// baseline (1541.208 us; speedup 1.0000x reference)
//
#include <hip/hip_runtime.h>
#include <cfloat>
#include <math.h>

#define NPTS   5000
#define BATCH  2
#define DIM    128
#define NBINS  10
#define BINSZ  500
#define TOPK   5
#define NCAND  8      // fp32 screening width (top-8 covers fp64 top-5 w/ huge margin)
#define ROTCOLS 100   // rotations stored [128, 100]; we use first NBINS/2 = 5

// ---------------- Kernel A: bin assignment + squared norms (fp64 acc) -----
#define KB_PTS 64
#define KB_STR 129
__global__ void k_bins(const float* __restrict__ pts, const float* __restrict__ rot,
                       int* __restrict__ bin_idx, double* __restrict__ na) {
    __shared__ float P[KB_PTS * KB_STR];
    __shared__ float rotL[DIM * 5];
    int tid = threadIdx.x;
    for (int f = tid; f < DIM * 5; f += 256)
        rotL[f] = rot[(f / 5) * ROTCOLS + (f % 5)];

    int p0  = blockIdx.x * KB_PTS;
    int npb = min(KB_PTS, BATCH * NPTS - p0);

    for (int f = tid; f < npb * DIM; f += 256) {
        int r = f >> 7, d = f & 127;
        P[r * KB_STR + d] = pts[(size_t)(p0 + r) * DIM + d];
    }
    __syncthreads();

    int p = tid >> 2;    // point within block
    int s = tid & 3;     // dim quarter
    double acc[5] = {0., 0., 0., 0., 0.};
    double sq = 0.;
    const float* row = &P[p * KB_STR + s * 32];
    for (int j = 0; j < 32; ++j) {
        double v = (double)row[j];
        sq += v * v;
        int d = s * 32 + j;
#pragma unroll
        for (int h = 0; h < 5; ++h) acc[h] += v * (double)rotL[d * 5 + h];
    }
#pragma unroll
    for (int m = 1; m < 4; m <<= 1) {
#pragma unroll
        for (int h = 0; h < 5; ++h) acc[h] += __shfl_xor(acc[h], m, 4);
        sq += __shfl_xor(sq, m, 4);
    }
    if (s == 0 && p < npb) {
        double best = acc[0]; int bc = 0;
#pragma unroll
        for (int c = 1; c < NBINS; ++c) {
            double v = (c < 5) ? acc[c] : -acc[c - 5];
            if (v > best) { best = v; bc = c; }
        }
        bin_idx[p0 + p] = bc;
        na[p0 + p] = sq;
    }
}

// ---------------- Kernel B: stable counting sort (== stable argsort) ------
__global__ void k_sort(const int* __restrict__ bin_idx, int* __restrict__ order) {
    const int b = blockIdx.x;
    const int t = threadIdx.x;               // 256 threads
    const int NPT = (NPTS + 255) / 256;      // 20
    int start = t * NPT;
    int end   = min(NPTS, start + NPT);

    int cnt[NBINS];
#pragma unroll
    for (int c = 0; c < NBINS; ++c) cnt[c] = 0;
    for (int i = start; i < end; ++i) {
        int c = bin_idx[b * NPTS + i];
#pragma unroll
        for (int k = 0; k < NBINS; ++k) cnt[k] += (c == k);
    }

    __shared__ int hist[NBINS * 256];
#pragma unroll
    for (int c = 0; c < NBINS; ++c) hist[c * 256 + t] = cnt[c];
    __syncthreads();

    int base = t * NBINS;
    int s = 0;
#pragma unroll
    for (int k = 0; k < NBINS; ++k) s += hist[base + k];
    __shared__ int scan[256];
    scan[t] = s;
    __syncthreads();
    for (int off = 1; off < 256; off <<= 1) {
        int v = (t >= off) ? scan[t - off] : 0;
        __syncthreads();
        scan[t] += v;
        __syncthreads();
    }
    int run = scan[t] - s;
#pragma unroll
    for (int k = 0; k < NBINS; ++k) { int h = hist[base + k]; hist[base + k] = run; run += h; }
    __syncthreads();

    int ofs[NBINS];
#pragma unroll
    for (int c = 0; c < NBINS; ++c) ofs[c] = hist[c * 256 + t];
    for (int i = start; i < end; ++i) {
        int c = bin_idx[b * NPTS + i];
        int pos = 0;
#pragma unroll
        for (int k = 0; k < NBINS; ++k) {
            if (c == k) pos = ofs[k];
            ofs[k] += (c == k);
        }
        order[b * NPTS + pos] = i;
    }
}

// ------- Kernel C: fp32 gram screen -> top-8 per row + zero-fill ----------
// Selection machinery mirrors the proven register-resident R5 pattern:
// plain float/int arrays, UNCONDITIONAL branchless insert chain, 32-bit shfls.
#define RT    16
#define NRT   32
#define CTILE 64
#define RSTR  132
#define NCT   8
#define ROWQ  (NPTS/4)

__launch_bounds__(256, 3)
__global__ void k_screen(const float* __restrict__ pts, const double* __restrict__ na,
                         const int* __restrict__ order, int* __restrict__ cand8,
                         float* __restrict__ out) {
    __shared__ float rowP[RT * RSTR];
    __shared__ float colP[CTILE * RSTR];
    __shared__ float naC[CTILE];
    __shared__ float naRs[RT];
    __shared__ int   ordR[RT];

    int blk   = blockIdx.x;
    int rt    = blk & (NRT - 1);
    int chunk = blk >> 5;          // 0..19
    int b     = chunk / NBINS;
    int c     = chunk % NBINS;
    int tid   = threadIdx.x;
    int row0  = rt * RT;
    int rowCount = min(RT, BINSZ - row0);   // 16, except last tile: 4

    const int*   ordBase = order + b * NPTS + c * BINSZ;
    const float* ptsB    = pts + (size_t)b * NPTS * DIM;

    for (int f = tid; f < rowCount * (DIM / 4); f += 256) {
        int r = f / (DIM / 4);
        int q = f % (DIM / 4);
        int g = ordBase[row0 + r];
        float4 v = *(const float4*)(ptsB + (size_t)g * DIM + q * 4);
        *(float4*)(&rowP[r * RSTR + q * 4]) = v;
    }
    if (tid < rowCount) {
        int g = ordBase[row0 + tid];
        ordR[tid] = g;
        naRs[tid] = (float)na[b * NPTS + g];
    }
    __syncthreads();

    int rg = tid >> 4;   // 0..15: this thread's row
    int cg = tid & 15;   // cols cg + 16*jj

    float naRr = (rg < rowCount) ? naRs[rg] : 0.f;

    float tv[NCAND];     // key = clamped fp32 d2, ascending best-first
    int   tl[NCAND];
#pragma unroll
    for (int k = 0; k < NCAND; ++k) { tv[k] = FLT_MAX; tl[k] = 0x7fffffff; }

    const int totalZ = rowCount * ROWQ;

    for (int ct = 0; ct < NCT; ++ct) {
        int col0 = ct * CTILE;
        int colCount = min(CTILE, BINSZ - col0);
        __syncthreads();
        for (int f = tid; f < colCount * (DIM / 4); f += 256) {
            int j = f / (DIM / 4);
            int q = f % (DIM / 4);
            int g = ordBase[col0 + j];
            float4 v = *(const float4*)(ptsB + (size_t)g * DIM + q * 4);
            *(float4*)(&colP[j * RSTR + q * 4]) = v;
        }
        if (tid < colCount) {
            int g = ordBase[col0 + tid];
            naC[tid] = (float)na[b * NPTS + g];
        }
        __syncthreads();

        // zero-fill slice ct: drains during this tile's compute
        {
            float4 z = make_float4(0.f, 0.f, 0.f, 0.f);
            int z0 = (ct * totalZ) / NCT, z1 = ((ct + 1) * totalZ) / NCT;
            for (int f = z0 + tid; f < z1; f += 256) {
                int r = f / ROWQ;
                int q = f - r * ROWQ;
                float* outRow = out + ((size_t)b * NPTS + ordR[r]) * NPTS;
                *(float4*)(outRow + 4 * q) = z;
            }
        }

        float acc[4];
#pragma unroll
        for (int jj = 0; jj < 4; ++jj) acc[jj] = 0.f;

        const float4* rowP4 = (const float4*)(rowP);
        const float4* colP4 = (const float4*)(colP);
        for (int q = 0; q < DIM / 4; ++q) {
            float4 a = rowP4[rg * (RSTR / 4) + q];
            float4 bb[4];
#pragma unroll
            for (int jj = 0; jj < 4; ++jj) bb[jj] = colP4[(cg + 16 * jj) * (RSTR / 4) + q];
#pragma unroll
            for (int jj = 0; jj < 4; ++jj) {
                acc[jj] += a.x * bb[jj].x + a.y * bb[jj].y
                         + a.z * bb[jj].z + a.w * bb[jj].w;
            }
        }

        // running bottom-8 (candidates arrive in increasing local idx; strict <
        // keeps the earlier index on equal keys)
#pragma unroll
        for (int jj = 0; jj < 4; ++jj) {
            int j = cg + 16 * jj;
            if (j < colCount) {
                float cv = fmaxf(naRr + naC[j] - 2.f * acc[jj], 1e-6f);
                int   cl = col0 + j;
#pragma unroll
                for (int k = 0; k < NCAND; ++k) {
                    bool lt = (cv < tv[k]);
                    float ov = tv[k]; int ol = tl[k];
                    if (lt) { tv[k] = cv; tl[k] = cl; cv = ov; cl = ol; }
                }
            }
        }
    }

    // merge the 16 column-threads' sorted lists (butterfly, width 16, 32-bit shfls)
#pragma unroll
    for (int m = 1; m < 16; m <<= 1) {
        float rv[NCAND]; int rl[NCAND];
#pragma unroll
        for (int k = 0; k < NCAND; ++k) {
            rv[k] = __shfl_xor(tv[k], m, 16);
            rl[k] = __shfl_xor(tl[k], m, 16);
        }
#pragma unroll
        for (int k = 0; k < NCAND; ++k) {
            float cv = rv[k]; int cl = rl[k];
#pragma unroll
            for (int s = 0; s < NCAND; ++s) {   // (key asc, idx asc) total order
                bool better = (cv < tv[s]) || (cv == tv[s] && cl < tl[s]);
                float ov = tv[s]; int ol = tl[s];
                if (better) { tv[s] = cv; tl[s] = cl; cv = ov; cl = ol; }
            }
        }
    }

    // write the 8 surviving local indices for this row
    if (cg == 0 && rg < rowCount) {
        int rowIdx = b * NPTS + c * BINSZ + row0 + rg;   // sorted-row index
#pragma unroll
        for (int k = 0; k < NCAND; ++k)
            cand8[rowIdx * NCAND + k] = tl[k];
    }
}

// ------- Kernel D: fp64 refine of 8 candidates/row + scatter --------------
#define RF_ROWS 4
__global__ void k_refine(const float* __restrict__ pts, const double* __restrict__ na,
                         const int* __restrict__ order, const int* __restrict__ cand8,
                         float* __restrict__ out) {
    __shared__ double keyL[RF_ROWS * NCAND];
    __shared__ int    dstL[RF_ROWS * NCAND];
    __shared__ int    lidL[RF_ROWS * NCAND];

    int tid  = threadIdx.x;
    int rsub = tid >> 6;                       // 0..3: row within block
    int row  = blockIdx.x * RF_ROWS + rsub;    // 0..9999 (sorted-row index)
    int lane = tid & 63;
    int cand = lane >> 3;                      // 0..7
    int dg   = lane & 7;                       // 0..7: 16-dim group

    int b   = row / NPTS;
    int pos = row - b * NPTS;
    int src = order[row];
    int binb = row - (pos % BINSZ);            // base of this row's bin in `order`
    int lid  = cand8[row * NCAND + cand];
    int dst  = order[binb + lid];

    const float4* ps4 = (const float4*)(pts + ((size_t)b * NPTS + src) * DIM);
    const float4* pd4 = (const float4*)(pts + ((size_t)b * NPTS + dst) * DIM);
    double g = 0.;
#pragma unroll
    for (int q = 0; q < 4; ++q) {
        float4 x = ps4[dg * 4 + q];
        float4 y = pd4[dg * 4 + q];
        g += (double)x.x * (double)y.x + (double)x.y * (double)y.y
           + (double)x.z * (double)y.z + (double)x.w * (double)y.w;
    }
#pragma unroll
    for (int m = 1; m < 8; m <<= 1) g += __shfl_xor(g, m, 8);

    if (dg == 0) {
        double key = fmax(na[b * NPTS + src] + na[b * NPTS + dst] - 2. * g, 1e-6);
        keyL[rsub * NCAND + cand] = key;
        dstL[rsub * NCAND + cand] = dst;
        lidL[rsub * NCAND + cand] = lid;
    }
    __syncthreads();

    if (lane == 0) {
        float* outRow = out + ((size_t)b * NPTS + src) * NPTS;
        bool used[NCAND];
#pragma unroll
        for (int k = 0; k < NCAND; ++k) used[k] = false;
#pragma unroll
        for (int k = 0; k < TOPK; ++k) {       // select k-th smallest (key, lid)
            int best = -1;
            double bk = DBL_MAX; int bl = 0x7fffffff;
            for (int m = 0; m < NCAND; ++m) {
                if (!used[m]) {
                    double kv = keyL[rsub * NCAND + m];
                    int    lv = lidL[rsub * NCAND + m];
                    if (kv < bk || (kv == bk && lv < bl)) { bk = kv; bl = lv; best = m; }
                }
            }
            used[best] = true;
            outRow[dstL[rsub * NCAND + best]] = (float)exp(-0.1 * sqrt(bk));
        }
    }
}

// ---------------- launch ----------------
extern "C" void kernel_launch(void* const* d_in, const int* in_sizes, int n_in,
                              void* d_out, int out_size, void* d_ws, size_t ws_size,
                              hipStream_t stream) {
    const float* pts = (const float*)d_in[0];   // [2,5000,128]
    const float* rot = (const float*)d_in[1];   // [128,100]
    float* out = (float*)d_out;                 // [2,5000,5000]

    double* na      = (double*)d_ws;                                    // 80000 B
    int*    bin_idx = (int*)((char*)d_ws + 80000);                      // 40000 B
    int*    order   = (int*)((char*)d_ws + 120000);                     // 40000 B
    int*    cand8   = (int*)((char*)d_ws + 160000);                     // 320000 B

    k_bins<<<(BATCH * NPTS + KB_PTS - 1) / KB_PTS, 256, 0, stream>>>(pts, rot, bin_idx, na);
    k_sort<<<BATCH, 256, 0, stream>>>(bin_idx, order);
    k_screen<<<BATCH * NBINS * NRT, 256, 0, stream>>>(pts, na, order, cand8, out);
    k_refine<<<(BATCH * NPTS) / RF_ROWS, 256, 0, stream>>>(pts, na, order, cand8, out);
}

// Round 8
// 1518.299 us; speedup vs baseline: 1.0151x; 1.0151x over previous
//
#include <hip/hip_runtime.h>
#include <cfloat>
#include <math.h>

#define NPTS   5000
#define BATCH  2
#define DIM    128
#define NBINS  10
#define BINSZ  500
#define TOPK   5
#define NCAND  8      // fp32 screening width
#define ROTCOLS 100   // rotations stored [128, 100]; we use first NBINS/2 = 5

// ---------------- Kernel A: bin assignment + squared norms (fp64 acc) -----
#define KB_PTS 64
#define KB_STR 129
__global__ void k_bins(const float* __restrict__ pts, const float* __restrict__ rot,
                       int* __restrict__ bin_idx, double* __restrict__ na) {
    __shared__ float P[KB_PTS * KB_STR];
    __shared__ float rotL[DIM * 5];
    int tid = threadIdx.x;
    for (int f = tid; f < DIM * 5; f += 256)
        rotL[f] = rot[(f / 5) * ROTCOLS + (f % 5)];

    int p0  = blockIdx.x * KB_PTS;
    int npb = min(KB_PTS, BATCH * NPTS - p0);

    for (int f = tid; f < npb * DIM; f += 256) {
        int r = f >> 7, d = f & 127;
        P[r * KB_STR + d] = pts[(size_t)(p0 + r) * DIM + d];
    }
    __syncthreads();

    int p = tid >> 2;    // point within block
    int s = tid & 3;     // dim quarter
    double acc[5] = {0., 0., 0., 0., 0.};
    double sq = 0.;
    const float* row = &P[p * KB_STR + s * 32];
    for (int j = 0; j < 32; ++j) {
        double v = (double)row[j];
        sq += v * v;
        int d = s * 32 + j;
#pragma unroll
        for (int h = 0; h < 5; ++h) acc[h] += v * (double)rotL[d * 5 + h];
    }
#pragma unroll
    for (int m = 1; m < 4; m <<= 1) {
#pragma unroll
        for (int h = 0; h < 5; ++h) acc[h] += __shfl_xor(acc[h], m, 4);
        sq += __shfl_xor(sq, m, 4);
    }
    if (s == 0 && p < npb) {
        double best = acc[0]; int bc = 0;
#pragma unroll
        for (int c = 1; c < NBINS; ++c) {
            double v = (c < 5) ? acc[c] : -acc[c - 5];
            if (v > best) { best = v; bc = c; }
        }
        bin_idx[p0 + p] = bc;
        na[p0 + p] = sq;
    }
}

// ---------------- Kernel B: stable counting sort (== stable argsort) ------
__global__ void k_sort(const int* __restrict__ bin_idx, int* __restrict__ order) {
    const int b = blockIdx.x;
    const int t = threadIdx.x;               // 256 threads
    const int NPT = (NPTS + 255) / 256;      // 20
    int start = t * NPT;
    int end   = min(NPTS, start + NPT);

    int cnt[NBINS];
#pragma unroll
    for (int c = 0; c < NBINS; ++c) cnt[c] = 0;
    for (int i = start; i < end; ++i) {
        int c = bin_idx[b * NPTS + i];
#pragma unroll
        for (int k = 0; k < NBINS; ++k) cnt[k] += (c == k);
    }

    __shared__ int hist[NBINS * 256];
#pragma unroll
    for (int c = 0; c < NBINS; ++c) hist[c * 256 + t] = cnt[c];
    __syncthreads();

    int base = t * NBINS;
    int s = 0;
#pragma unroll
    for (int k = 0; k < NBINS; ++k) s += hist[base + k];
    __shared__ int scan[256];
    scan[t] = s;
    __syncthreads();
    for (int off = 1; off < 256; off <<= 1) {
        int v = (t >= off) ? scan[t - off] : 0;
        __syncthreads();
        scan[t] += v;
        __syncthreads();
    }
    int run = scan[t] - s;
#pragma unroll
    for (int k = 0; k < NBINS; ++k) { int h = hist[base + k]; hist[base + k] = run; run += h; }
    __syncthreads();

    int ofs[NBINS];
#pragma unroll
    for (int c = 0; c < NBINS; ++c) ofs[c] = hist[c * 256 + t];
    for (int i = start; i < end; ++i) {
        int c = bin_idx[b * NPTS + i];
        int pos = 0;
#pragma unroll
        for (int k = 0; k < NBINS; ++k) {
            if (c == k) pos = ofs[k];
            ofs[k] += (c == k);
        }
        order[b * NPTS + pos] = i;
    }
}

// ------- Kernel C: fp32 gram screen -> top-8 per row + zero-fill ----------
// ALL candidate state in named scalars (t0..t7 / l0..l7): arrays of width 8
// were demoted to scratch by the compiler in R6/R7 (FETCH/WRITE ~2 GB each);
// scalars cannot be.
#define RT    16
#define NRT   32
#define CTILE 64
#define RSTR  132
#define NCT   8
#define ROWQ  (NPTS/4)

// branchless sorted-insert step: (cv,cl) vs slot (tk,lk), strict < (ties keep slot)
#define CSWAP(cv, cl, tk, lk) { bool _lt = (cv) < (tk);                        \
    float _ov = (tk); int _ol = (lk);                                          \
    if (_lt) { (tk) = (cv); (lk) = (cl); (cv) = _ov; (cl) = _ol; } }
#define INSERT8(cv, cl) { CSWAP(cv, cl, t0, l0) CSWAP(cv, cl, t1, l1)          \
    CSWAP(cv, cl, t2, l2) CSWAP(cv, cl, t3, l3) CSWAP(cv, cl, t4, l4)          \
    CSWAP(cv, cl, t5, l5) CSWAP(cv, cl, t6, l6) CSWAP(cv, cl, t7, l7) }

// tie-aware step for the cross-lane merge: (key asc, idx asc) total order
#define MSWAP(cv, cl, tk, lk) { bool _bt = ((cv) < (tk)) ||                    \
    ((cv) == (tk) && (cl) < (lk));                                             \
    float _ov = (tk); int _ol = (lk);                                          \
    if (_bt) { (tk) = (cv); (lk) = (cl); (cv) = _ov; (cl) = _ol; } }
#define MINSERT8(cv, cl) { MSWAP(cv, cl, t0, l0) MSWAP(cv, cl, t1, l1)         \
    MSWAP(cv, cl, t2, l2) MSWAP(cv, cl, t3, l3) MSWAP(cv, cl, t4, l4)         \
    MSWAP(cv, cl, t5, l5) MSWAP(cv, cl, t6, l6) MSWAP(cv, cl, t7, l7) }

__launch_bounds__(256, 3)
__global__ void k_screen(const float* __restrict__ pts, const double* __restrict__ na,
                         const int* __restrict__ order, int* __restrict__ cand8,
                         float* __restrict__ out) {
    __shared__ float rowP[RT * RSTR];
    __shared__ float colP[CTILE * RSTR];
    __shared__ float naC[CTILE];
    __shared__ float naRs[RT];
    __shared__ int   ordR[RT];

    int blk   = blockIdx.x;
    int rt    = blk & (NRT - 1);
    int chunk = blk >> 5;          // 0..19
    int b     = chunk / NBINS;
    int c     = chunk % NBINS;
    int tid   = threadIdx.x;
    int row0  = rt * RT;
    int rowCount = min(RT, BINSZ - row0);   // 16, except last tile: 4

    const int*   ordBase = order + b * NPTS + c * BINSZ;
    const float* ptsB    = pts + (size_t)b * NPTS * DIM;

    for (int f = tid; f < rowCount * (DIM / 4); f += 256) {
        int r = f / (DIM / 4);
        int q = f % (DIM / 4);
        int g = ordBase[row0 + r];
        float4 v = *(const float4*)(ptsB + (size_t)g * DIM + q * 4);
        *(float4*)(&rowP[r * RSTR + q * 4]) = v;
    }
    if (tid < rowCount) {
        int g = ordBase[row0 + tid];
        ordR[tid] = g;
        naRs[tid] = (float)na[b * NPTS + g];
    }
    __syncthreads();

    int rg = tid >> 4;   // 0..15: this thread's row
    int cg = tid & 15;   // cols cg + 16*jj

    float naRr = (rg < rowCount) ? naRs[rg] : 0.f;

    float t0 = FLT_MAX, t1 = FLT_MAX, t2 = FLT_MAX, t3 = FLT_MAX,
          t4 = FLT_MAX, t5 = FLT_MAX, t6 = FLT_MAX, t7 = FLT_MAX;
    int   l0 = 0x7fffffff, l1 = 0x7fffffff, l2 = 0x7fffffff, l3 = 0x7fffffff,
          l4 = 0x7fffffff, l5 = 0x7fffffff, l6 = 0x7fffffff, l7 = 0x7fffffff;

    const int totalZ = rowCount * ROWQ;

    for (int ct = 0; ct < NCT; ++ct) {
        int col0 = ct * CTILE;
        int colCount = min(CTILE, BINSZ - col0);
        __syncthreads();
        for (int f = tid; f < colCount * (DIM / 4); f += 256) {
            int j = f / (DIM / 4);
            int q = f % (DIM / 4);
            int g = ordBase[col0 + j];
            float4 v = *(const float4*)(ptsB + (size_t)g * DIM + q * 4);
            *(float4*)(&colP[j * RSTR + q * 4]) = v;
        }
        if (tid < colCount) {
            int g = ordBase[col0 + tid];
            naC[tid] = (float)na[b * NPTS + g];
        }
        __syncthreads();

        // zero-fill slice ct: drains during this tile's compute
        {
            float4 z = make_float4(0.f, 0.f, 0.f, 0.f);
            int z0 = (ct * totalZ) / NCT, z1 = ((ct + 1) * totalZ) / NCT;
            for (int f = z0 + tid; f < z1; f += 256) {
                int r = f / ROWQ;
                int q = f - r * ROWQ;
                float* outRow = out + ((size_t)b * NPTS + ordR[r]) * NPTS;
                *(float4*)(outRow + 4 * q) = z;
            }
        }

        float acc0 = 0.f, acc1 = 0.f, acc2 = 0.f, acc3 = 0.f;

        const float4* rowP4 = (const float4*)(rowP);
        const float4* colP4 = (const float4*)(colP);
        for (int q = 0; q < DIM / 4; ++q) {
            float4 a  = rowP4[rg * (RSTR / 4) + q];
            float4 b0 = colP4[(cg +  0) * (RSTR / 4) + q];
            float4 b1 = colP4[(cg + 16) * (RSTR / 4) + q];
            float4 b2 = colP4[(cg + 32) * (RSTR / 4) + q];
            float4 b3 = colP4[(cg + 48) * (RSTR / 4) + q];
            acc0 += a.x * b0.x + a.y * b0.y + a.z * b0.z + a.w * b0.w;
            acc1 += a.x * b1.x + a.y * b1.y + a.z * b1.z + a.w * b1.w;
            acc2 += a.x * b2.x + a.y * b2.y + a.z * b2.z + a.w * b2.w;
            acc3 += a.x * b3.x + a.y * b3.y + a.z * b3.z + a.w * b3.w;
        }

        // running bottom-8 (candidates arrive in increasing local idx; strict <
        // keeps the earlier index on equal keys)
#pragma unroll
        for (int jj = 0; jj < 4; ++jj) {
            int j = cg + 16 * jj;
            if (j < colCount) {
                float av = (jj == 0) ? acc0 : (jj == 1) ? acc1 : (jj == 2) ? acc2 : acc3;
                float cv = fmaxf(naRr + naC[j] - 2.f * av, 1e-6f);
                int   cl = col0 + j;
                INSERT8(cv, cl)
            }
        }
    }

    // merge the 16 column-threads' sorted lists (butterfly, width 16)
#pragma unroll
    for (int m = 1; m < 16; m <<= 1) {
        float r0 = __shfl_xor(t0, m, 16), r1 = __shfl_xor(t1, m, 16),
              r2 = __shfl_xor(t2, m, 16), r3 = __shfl_xor(t3, m, 16),
              r4 = __shfl_xor(t4, m, 16), r5 = __shfl_xor(t5, m, 16),
              r6 = __shfl_xor(t6, m, 16), r7 = __shfl_xor(t7, m, 16);
        int   s0 = __shfl_xor(l0, m, 16), s1 = __shfl_xor(l1, m, 16),
              s2 = __shfl_xor(l2, m, 16), s3 = __shfl_xor(l3, m, 16),
              s4 = __shfl_xor(l4, m, 16), s5 = __shfl_xor(l5, m, 16),
              s6 = __shfl_xor(l6, m, 16), s7 = __shfl_xor(l7, m, 16);
        MINSERT8(r0, s0) MINSERT8(r1, s1) MINSERT8(r2, s2) MINSERT8(r3, s3)
        MINSERT8(r4, s4) MINSERT8(r5, s5) MINSERT8(r6, s6) MINSERT8(r7, s7)
    }

    // write the 8 surviving local indices for this row
    if (cg == 0 && rg < rowCount) {
        int rowIdx = b * NPTS + c * BINSZ + row0 + rg;   // sorted-row index
        int* o = cand8 + rowIdx * NCAND;
        o[0] = l0; o[1] = l1; o[2] = l2; o[3] = l3;
        o[4] = l4; o[5] = l5; o[6] = l6; o[7] = l7;
    }
}

// ------- Kernel D: fp64 refine of 8 candidates/row + scatter --------------
#define RF_ROWS 4
__global__ void k_refine(const float* __restrict__ pts, const double* __restrict__ na,
                         const int* __restrict__ order, const int* __restrict__ cand8,
                         float* __restrict__ out) {
    __shared__ double keyL[RF_ROWS * NCAND];
    __shared__ int    dstL[RF_ROWS * NCAND];
    __shared__ int    lidL[RF_ROWS * NCAND];

    int tid  = threadIdx.x;
    int rsub = tid >> 6;                       // 0..3: row within block
    int row  = blockIdx.x * RF_ROWS + rsub;    // 0..9999 (sorted-row index)
    int lane = tid & 63;
    int cand = lane >> 3;                      // 0..7
    int dg   = lane & 7;                       // 0..7: 16-dim group

    int b   = row / NPTS;
    int pos = row - b * NPTS;
    int src = order[row];
    int binb = row - (pos % BINSZ);            // base of this row's bin in `order`
    int lid  = cand8[row * NCAND + cand];
    int dst  = order[binb + lid];

    const float4* ps4 = (const float4*)(pts + ((size_t)b * NPTS + src) * DIM);
    const float4* pd4 = (const float4*)(pts + ((size_t)b * NPTS + dst) * DIM);
    double g = 0.;
#pragma unroll
    for (int q = 0; q < 4; ++q) {
        float4 x = ps4[dg * 4 + q];
        float4 y = pd4[dg * 4 + q];
        g += (double)x.x * (double)y.x + (double)x.y * (double)y.y
           + (double)x.z * (double)y.z + (double)x.w * (double)y.w;
    }
#pragma unroll
    for (int m = 1; m < 8; m <<= 1) g += __shfl_xor(g, m, 8);

    if (dg == 0) {
        double key = fmax(na[b * NPTS + src] + na[b * NPTS + dst] - 2. * g, 1e-6);
        keyL[rsub * NCAND + cand] = key;
        dstL[rsub * NCAND + cand] = dst;
        lidL[rsub * NCAND + cand] = lid;
    }
    __syncthreads();

    if (lane == 0) {
        float* outRow = out + ((size_t)b * NPTS + src) * NPTS;
        bool used[NCAND];
#pragma unroll
        for (int k = 0; k < NCAND; ++k) used[k] = false;
#pragma unroll
        for (int k = 0; k < TOPK; ++k) {       // select k-th smallest (key, lid)
            int best = -1;
            double bk = DBL_MAX; int bl = 0x7fffffff;
            for (int m = 0; m < NCAND; ++m) {
                if (!used[m]) {
                    double kv = keyL[rsub * NCAND + m];
                    int    lv = lidL[rsub * NCAND + m];
                    if (kv < bk || (kv == bk && lv < bl)) { bk = kv; bl = lv; best = m; }
                }
            }
            used[best] = true;
            outRow[dstL[rsub * NCAND + best]] = (float)exp(-0.1 * sqrt(bk));
        }
    }
}

// ---------------- launch ----------------
extern "C" void kernel_launch(void* const* d_in, const int* in_sizes, int n_in,
                              void* d_out, int out_size, void* d_ws, size_t ws_size,
                              hipStream_t stream) {
    const float* pts = (const float*)d_in[0];   // [2,5000,128]
    const float* rot = (const float*)d_in[1];   // [128,100]
    float* out = (float*)d_out;                 // [2,5000,5000]

    double* na      = (double*)d_ws;                                    // 80000 B
    int*    bin_idx = (int*)((char*)d_ws + 80000);                      // 40000 B
    int*    order   = (int*)((char*)d_ws + 120000);                     // 40000 B
    int*    cand8   = (int*)((char*)d_ws + 160000);                     // 320000 B

    k_bins<<<(BATCH * NPTS + KB_PTS - 1) / KB_PTS, 256, 0, stream>>>(pts, rot, bin_idx, na);
    k_sort<<<BATCH, 256, 0, stream>>>(bin_idx, order);
    k_screen<<<BATCH * NBINS * NRT, 256, 0, stream>>>(pts, na, order, cand8, out);
    k_refine<<<(BATCH * NPTS) / RF_ROWS, 256, 0, stream>>>(pts, na, order, cand8, out);
}

// Round 9
// 1417.381 us; speedup vs baseline: 1.0874x; 1.0712x over previous
//
#include <hip/hip_runtime.h>
#include <cfloat>
#include <math.h>

#define NPTS   5000
#define BATCH  2
#define DIM    128
#define NBINS  10
#define BINSZ  500
#define TOPK   5
#define NCAND  8      // fp32 screening width; fp64 refine of these 8 in-kernel
#define ROTCOLS 100   // rotations stored [128, 100]; we use first NBINS/2 = 5

// ---------------- Kernel A: bin assignment + squared norms (fp64 acc) -----
#define KB_PTS 64
#define KB_STR 129
__global__ void k_bins(const float* __restrict__ pts, const float* __restrict__ rot,
                       int* __restrict__ bin_idx, double* __restrict__ na) {
    __shared__ float P[KB_PTS * KB_STR];
    __shared__ float rotL[DIM * 5];
    int tid = threadIdx.x;
    for (int f = tid; f < DIM * 5; f += 256)
        rotL[f] = rot[(f / 5) * ROTCOLS + (f % 5)];

    int p0  = blockIdx.x * KB_PTS;
    int npb = min(KB_PTS, BATCH * NPTS - p0);

    for (int f = tid; f < npb * DIM; f += 256) {
        int r = f >> 7, d = f & 127;
        P[r * KB_STR + d] = pts[(size_t)(p0 + r) * DIM + d];
    }
    __syncthreads();

    int p = tid >> 2;    // point within block
    int s = tid & 3;     // dim quarter
    double acc[5] = {0., 0., 0., 0., 0.};
    double sq = 0.;
    const float* row = &P[p * KB_STR + s * 32];
    for (int j = 0; j < 32; ++j) {
        double v = (double)row[j];
        sq += v * v;
        int d = s * 32 + j;
#pragma unroll
        for (int h = 0; h < 5; ++h) acc[h] += v * (double)rotL[d * 5 + h];
    }
#pragma unroll
    for (int m = 1; m < 4; m <<= 1) {
#pragma unroll
        for (int h = 0; h < 5; ++h) acc[h] += __shfl_xor(acc[h], m, 4);
        sq += __shfl_xor(sq, m, 4);
    }
    if (s == 0 && p < npb) {
        double best = acc[0]; int bc = 0;
#pragma unroll
        for (int c = 1; c < NBINS; ++c) {
            double v = (c < 5) ? acc[c] : -acc[c - 5];
            if (v > best) { best = v; bc = c; }
        }
        bin_idx[p0 + p] = bc;
        na[p0 + p] = sq;
    }
}

// ---------------- Kernel B: stable counting sort (== stable argsort) ------
__global__ void k_sort(const int* __restrict__ bin_idx, int* __restrict__ order) {
    const int b = blockIdx.x;
    const int t = threadIdx.x;               // 256 threads
    const int NPT = (NPTS + 255) / 256;      // 20
    int start = t * NPT;
    int end   = min(NPTS, start + NPT);

    int cnt[NBINS];
#pragma unroll
    for (int c = 0; c < NBINS; ++c) cnt[c] = 0;
    for (int i = start; i < end; ++i) {
        int c = bin_idx[b * NPTS + i];
#pragma unroll
        for (int k = 0; k < NBINS; ++k) cnt[k] += (c == k);
    }

    __shared__ int hist[NBINS * 256];
#pragma unroll
    for (int c = 0; c < NBINS; ++c) hist[c * 256 + t] = cnt[c];
    __syncthreads();

    int base = t * NBINS;
    int s = 0;
#pragma unroll
    for (int k = 0; k < NBINS; ++k) s += hist[base + k];
    __shared__ int scan[256];
    scan[t] = s;
    __syncthreads();
    for (int off = 1; off < 256; off <<= 1) {
        int v = (t >= off) ? scan[t - off] : 0;
        __syncthreads();
        scan[t] += v;
        __syncthreads();
    }
    int run = scan[t] - s;
#pragma unroll
    for (int k = 0; k < NBINS; ++k) { int h = hist[base + k]; hist[base + k] = run; run += h; }
    __syncthreads();

    int ofs[NBINS];
#pragma unroll
    for (int c = 0; c < NBINS; ++c) ofs[c] = hist[c * 256 + t];
    for (int i = start; i < end; ++i) {
        int c = bin_idx[b * NPTS + i];
        int pos = 0;
#pragma unroll
        for (int k = 0; k < NBINS; ++k) {
            if (c == k) pos = ofs[k];
            ofs[k] += (c == k);
        }
        order[b * NPTS + pos] = i;
    }
}

// -- Kernel C: fp32 screen -> top-8 -> FUSED fp64 refine + scatter ---------
// Memory-visible shape identical to the proven R5 kernel: reads pts/na/order,
// writes ONLY `out` (zero-fill + 5 values/row). No candidate buffer, no
// second consumer kernel.
#define RT    16
#define NRT   32
#define CTILE 64
#define RSTR  132
#define NCT   8
#define ROWQ  (NPTS/4)

#define CSWAP(cv, cl, tk, lk) { bool _lt = (cv) < (tk);                        \
    float _ov = (tk); int _ol = (lk);                                          \
    if (_lt) { (tk) = (cv); (lk) = (cl); (cv) = _ov; (cl) = _ol; } }
#define INSERT8(cv, cl) { CSWAP(cv, cl, t0, l0) CSWAP(cv, cl, t1, l1)          \
    CSWAP(cv, cl, t2, l2) CSWAP(cv, cl, t3, l3) CSWAP(cv, cl, t4, l4)          \
    CSWAP(cv, cl, t5, l5) CSWAP(cv, cl, t6, l6) CSWAP(cv, cl, t7, l7) }

#define MSWAP(cv, cl, tk, lk) { bool _bt = ((cv) < (tk)) ||                    \
    ((cv) == (tk) && (cl) < (lk));                                             \
    float _ov = (tk); int _ol = (lk);                                          \
    if (_bt) { (tk) = (cv); (lk) = (cl); (cv) = _ov; (cl) = _ol; } }
#define MINSERT8(cv, cl) { MSWAP(cv, cl, t0, l0) MSWAP(cv, cl, t1, l1)         \
    MSWAP(cv, cl, t2, l2) MSWAP(cv, cl, t3, l3) MSWAP(cv, cl, t4, l4)         \
    MSWAP(cv, cl, t5, l5) MSWAP(cv, cl, t6, l6) MSWAP(cv, cl, t7, l7) }

__launch_bounds__(256, 3)
__global__ void k_screen(const float* __restrict__ pts, const double* __restrict__ na,
                         const int* __restrict__ order, float* __restrict__ out) {
    __shared__ float rowP[RT * RSTR];
    __shared__ float colP[CTILE * RSTR];
    __shared__ float naC[CTILE];
    __shared__ float naRs[RT];
    __shared__ int   ordR[RT];

    int blk   = blockIdx.x;
    int rt    = blk & (NRT - 1);
    int chunk = blk >> 5;          // 0..19
    int b     = chunk / NBINS;
    int c     = chunk % NBINS;
    int tid   = threadIdx.x;
    int row0  = rt * RT;
    int rowCount = min(RT, BINSZ - row0);   // 16, except last tile: 4

    const int*   ordBase = order + b * NPTS + c * BINSZ;
    const float* ptsB    = pts + (size_t)b * NPTS * DIM;

    for (int f = tid; f < rowCount * (DIM / 4); f += 256) {
        int r = f / (DIM / 4);
        int q = f % (DIM / 4);
        int g = ordBase[row0 + r];
        float4 v = *(const float4*)(ptsB + (size_t)g * DIM + q * 4);
        *(float4*)(&rowP[r * RSTR + q * 4]) = v;
    }
    if (tid < rowCount) {
        int g = ordBase[row0 + tid];
        ordR[tid] = g;
        naRs[tid] = (float)na[b * NPTS + g];
    }
    __syncthreads();

    int rg = tid >> 4;   // 0..15: this thread's row
    int cg = tid & 15;   // cols cg + 16*jj

    float naRr = (rg < rowCount) ? naRs[rg] : 0.f;

    float t0 = FLT_MAX, t1 = FLT_MAX, t2 = FLT_MAX, t3 = FLT_MAX,
          t4 = FLT_MAX, t5 = FLT_MAX, t6 = FLT_MAX, t7 = FLT_MAX;
    int   l0 = 0x7fffffff, l1 = 0x7fffffff, l2 = 0x7fffffff, l3 = 0x7fffffff,
          l4 = 0x7fffffff, l5 = 0x7fffffff, l6 = 0x7fffffff, l7 = 0x7fffffff;

    const int totalZ = rowCount * ROWQ;

    for (int ct = 0; ct < NCT; ++ct) {
        int col0 = ct * CTILE;
        int colCount = min(CTILE, BINSZ - col0);
        __syncthreads();
        for (int f = tid; f < colCount * (DIM / 4); f += 256) {
            int j = f / (DIM / 4);
            int q = f % (DIM / 4);
            int g = ordBase[col0 + j];
            float4 v = *(const float4*)(ptsB + (size_t)g * DIM + q * 4);
            *(float4*)(&colP[j * RSTR + q * 4]) = v;
        }
        if (tid < colCount) {
            int g = ordBase[col0 + tid];
            naC[tid] = (float)na[b * NPTS + g];
        }
        __syncthreads();

        // zero-fill slice ct (drains during this tile's compute)
        {
            float4 z = make_float4(0.f, 0.f, 0.f, 0.f);
            int z0 = (ct * totalZ) / NCT, z1 = ((ct + 1) * totalZ) / NCT;
            for (int f = z0 + tid; f < z1; f += 256) {
                int r = f / ROWQ;
                int q = f - r * ROWQ;
                float* outRow = out + ((size_t)b * NPTS + ordR[r]) * NPTS;
                *(float4*)(outRow + 4 * q) = z;
            }
        }

        float acc0 = 0.f, acc1 = 0.f, acc2 = 0.f, acc3 = 0.f;
        const float4* rowP4 = (const float4*)(rowP);
        const float4* colP4 = (const float4*)(colP);
        for (int q = 0; q < DIM / 4; ++q) {
            float4 a  = rowP4[rg * (RSTR / 4) + q];
            float4 b0 = colP4[(cg +  0) * (RSTR / 4) + q];
            float4 b1 = colP4[(cg + 16) * (RSTR / 4) + q];
            float4 b2 = colP4[(cg + 32) * (RSTR / 4) + q];
            float4 b3 = colP4[(cg + 48) * (RSTR / 4) + q];
            acc0 += a.x * b0.x + a.y * b0.y + a.z * b0.z + a.w * b0.w;
            acc1 += a.x * b1.x + a.y * b1.y + a.z * b1.z + a.w * b1.w;
            acc2 += a.x * b2.x + a.y * b2.y + a.z * b2.z + a.w * b2.w;
            acc3 += a.x * b3.x + a.y * b3.y + a.z * b3.z + a.w * b3.w;
        }

#pragma unroll
        for (int jj = 0; jj < 4; ++jj) {
            int j = cg + 16 * jj;
            if (j < colCount) {
                float av = (jj == 0) ? acc0 : (jj == 1) ? acc1 : (jj == 2) ? acc2 : acc3;
                float cv = fmaxf(naRr + naC[j] - 2.f * av, 1e-6f);
                int   cl = col0 + j;
                INSERT8(cv, cl)
            }
        }
    }

    // merge the 16 column-threads' sorted lists (butterfly, width 16)
#pragma unroll
    for (int m = 1; m < 16; m <<= 1) {
        float r0 = __shfl_xor(t0, m, 16), r1 = __shfl_xor(t1, m, 16),
              r2 = __shfl_xor(t2, m, 16), r3 = __shfl_xor(t3, m, 16),
              r4 = __shfl_xor(t4, m, 16), r5 = __shfl_xor(t5, m, 16),
              r6 = __shfl_xor(t6, m, 16), r7 = __shfl_xor(t7, m, 16);
        int   s0 = __shfl_xor(l0, m, 16), s1 = __shfl_xor(l1, m, 16),
              s2 = __shfl_xor(l2, m, 16), s3 = __shfl_xor(l3, m, 16),
              s4 = __shfl_xor(l4, m, 16), s5 = __shfl_xor(l5, m, 16),
              s6 = __shfl_xor(l6, m, 16), s7 = __shfl_xor(l7, m, 16);
        MINSERT8(r0, s0) MINSERT8(r1, s1) MINSERT8(r2, s2) MINSERT8(r3, s3)
        MINSERT8(r4, s4) MINSERT8(r5, s5) MINSERT8(r6, s6) MINSERT8(r7, s7)
    }

    __syncthreads();   // drain last zero slice before value scatter

    // FUSED fp64 refine: lanes cg 0..7 of each row-group each own one of the
    // 8 screened candidates; recompute exact fp64 key; rank; top-5 scatter.
    if (rg < rowCount && cg < NCAND) {
        int lid = l0;
        lid = (cg == 1) ? l1 : lid;  lid = (cg == 2) ? l2 : lid;
        lid = (cg == 3) ? l3 : lid;  lid = (cg == 4) ? l4 : lid;
        lid = (cg == 5) ? l5 : lid;  lid = (cg == 6) ? l6 : lid;
        lid = (cg == 7) ? l7 : lid;

        int gdst = ordBase[lid];
        int src  = ordR[rg];
        double nr = na[(size_t)b * NPTS + src];
        double nd = na[(size_t)b * NPTS + gdst];

        const float4* rowP4 = (const float4*)(rowP);
        const float4* pd4   = (const float4*)(ptsB + (size_t)gdst * DIM);
        double dot = 0.;
        for (int q = 0; q < DIM / 4; ++q) {
            float4 x = rowP4[rg * (RSTR / 4) + q];
            float4 y = pd4[q];
            dot += (double)x.x * (double)y.x + (double)x.y * (double)y.y
                 + (double)x.z * (double)y.z + (double)x.w * (double)y.w;
        }
        double key = fmax(nr + nd - 2. * dot, 1e-6);

        // rank by (key asc, lid asc) among the 8 candidate lanes
        int rank = 0;
#pragma unroll
        for (int m = 1; m < NCAND; ++m) {
            double ok = __shfl_xor(key, m, NCAND);
            int    ol = __shfl_xor(lid, m, NCAND);
            rank += (ok < key) || (ok == key && ol < lid) ? 1 : 0;
        }
        if (rank < TOPK) {
            out[((size_t)b * NPTS + src) * NPTS + gdst] = (float)exp(-0.1 * sqrt(key));
        }
    }
}

// ---------------- launch ----------------
extern "C" void kernel_launch(void* const* d_in, const int* in_sizes, int n_in,
                              void* d_out, int out_size, void* d_ws, size_t ws_size,
                              hipStream_t stream) {
    const float* pts = (const float*)d_in[0];   // [2,5000,128]
    const float* rot = (const float*)d_in[1];   // [128,100]
    float* out = (float*)d_out;                 // [2,5000,5000]

    double* na      = (double*)d_ws;                                    // 80000 B
    int*    bin_idx = (int*)((char*)d_ws + 80000);                      // 40000 B
    int*    order   = (int*)((char*)d_ws + 120000);                     // 40000 B

    k_bins<<<(BATCH * NPTS + KB_PTS - 1) / KB_PTS, 256, 0, stream>>>(pts, rot, bin_idx, na);
    k_sort<<<BATCH, 256, 0, stream>>>(bin_idx, order);
    k_screen<<<BATCH * NBINS * NRT, 256, 0, stream>>>(pts, na, order, out);
}

// Round 10
// 296.440 us; speedup vs baseline: 5.1991x; 4.7813x over previous
//
#include <hip/hip_runtime.h>
#include <cfloat>
#include <math.h>

#define NPTS   5000
#define BATCH  2
#define DIM    128
#define NBINS  10
#define BINSZ  500
#define TOPK   5
#define ROTCOLS 100   // rotations stored [128, 100]; we use first NBINS/2 = 5

// ---------------- Kernel A: bin assignment + squared norms (fp64 acc) -----
#define KB_PTS 64
#define KB_STR 129
__global__ void k_bins(const float* __restrict__ pts, const float* __restrict__ rot,
                       int* __restrict__ bin_idx, double* __restrict__ na) {
    __shared__ float P[KB_PTS * KB_STR];
    __shared__ float rotL[DIM * 5];
    int tid = threadIdx.x;
    for (int f = tid; f < DIM * 5; f += 256)
        rotL[f] = rot[(f / 5) * ROTCOLS + (f % 5)];

    int p0  = blockIdx.x * KB_PTS;
    int npb = min(KB_PTS, BATCH * NPTS - p0);

    for (int f = tid; f < npb * DIM; f += 256) {
        int r = f >> 7, d = f & 127;
        P[r * KB_STR + d] = pts[(size_t)(p0 + r) * DIM + d];
    }
    __syncthreads();

    int p = tid >> 2;    // point within block
    int s = tid & 3;     // dim quarter
    double acc[5] = {0., 0., 0., 0., 0.};
    double sq = 0.;
    const float* row = &P[p * KB_STR + s * 32];
    for (int j = 0; j < 32; ++j) {
        double v = (double)row[j];
        sq += v * v;
        int d = s * 32 + j;
#pragma unroll
        for (int h = 0; h < 5; ++h) acc[h] += v * (double)rotL[d * 5 + h];
    }
#pragma unroll
    for (int m = 1; m < 4; m <<= 1) {
#pragma unroll
        for (int h = 0; h < 5; ++h) acc[h] += __shfl_xor(acc[h], m, 4);
        sq += __shfl_xor(sq, m, 4);
    }
    if (s == 0 && p < npb) {
        double best = acc[0]; int bc = 0;
#pragma unroll
        for (int c = 1; c < NBINS; ++c) {
            double v = (c < 5) ? acc[c] : -acc[c - 5];
            if (v > best) { best = v; bc = c; }
        }
        bin_idx[p0 + p] = bc;
        na[p0 + p] = sq;
    }
}

// ---------------- Kernel B: stable counting sort (== stable argsort) ------
__global__ void k_sort(const int* __restrict__ bin_idx, int* __restrict__ order) {
    const int b = blockIdx.x;
    const int t = threadIdx.x;               // 256 threads
    const int NPT = (NPTS + 255) / 256;      // 20
    int start = t * NPT;
    int end   = min(NPTS, start + NPT);

    int cnt[NBINS];
#pragma unroll
    for (int c = 0; c < NBINS; ++c) cnt[c] = 0;
    for (int i = start; i < end; ++i) {
        int c = bin_idx[b * NPTS + i];
#pragma unroll
        for (int k = 0; k < NBINS; ++k) cnt[k] += (c == k);
    }

    __shared__ int hist[NBINS * 256];
#pragma unroll
    for (int c = 0; c < NBINS; ++c) hist[c * 256 + t] = cnt[c];
    __syncthreads();

    int base = t * NBINS;
    int s = 0;
#pragma unroll
    for (int k = 0; k < NBINS; ++k) s += hist[base + k];
    __shared__ int scan[256];
    scan[t] = s;
    __syncthreads();
    for (int off = 1; off < 256; off <<= 1) {
        int v = (t >= off) ? scan[t - off] : 0;
        __syncthreads();
        scan[t] += v;
        __syncthreads();
    }
    int run = scan[t] - s;
#pragma unroll
    for (int k = 0; k < NBINS; ++k) { int h = hist[base + k]; hist[base + k] = run; run += h; }
    __syncthreads();

    int ofs[NBINS];
#pragma unroll
    for (int c = 0; c < NBINS; ++c) ofs[c] = hist[c * 256 + t];
    for (int i = start; i < end; ++i) {
        int c = bin_idx[b * NPTS + i];
        int pos = 0;
#pragma unroll
        for (int k = 0; k < NBINS; ++k) {
            if (c == k) pos = ofs[k];
            ofs[k] += (c == k);
        }
        order[b * NPTS + pos] = i;
    }
}

// -- Kernel C: fp64 gram (rowP staged as fp64) + top-5 + zero-fill/scatter --
// R5 base (proven 132us, absmax 0.0) with:
//  * rowP staged as DOUBLE in LDS: A-side f32->f64 converts hoisted (8/thread
//    total instead of 1024)
//  * 2 rows x 2 cols per thread (rows {rg,rg+8}, cols {cg,cg+32}): B-side
//    converts amortized 2x
// Key arithmetic keeps R5's exact expression order -> bit-identical decisions.
#define RT    16
#define NRT   32
#define CTILE 64
#define RSTRD 130      // rowPd stride in doubles (1040 B rows, 16B-aligned)
#define CSTR  132      // colP stride in floats
#define NCT   8
#define ROWQ  (NPTS/4)

__launch_bounds__(256, 3)
__global__ void k_chunks(const float* __restrict__ pts, const double* __restrict__ na,
                         const int* __restrict__ order, float* __restrict__ out) {
    __shared__ double rowPd[RT * RSTRD];    // 16640 B
    __shared__ float  colP[CTILE * CSTR];   // 33792 B
    __shared__ double naC[CTILE];           // 512 B
    __shared__ double naRs[RT];             // 128 B
    __shared__ int    ordR[RT];             // 64 B   -> 51.1 KB, 3 blocks/CU

    int blk   = blockIdx.x;
    int rt    = blk & (NRT - 1);
    int chunk = blk >> 5;          // 0..19
    int b     = chunk / NBINS;
    int c     = chunk % NBINS;
    int tid   = threadIdx.x;
    int row0  = rt * RT;
    int rowCount = min(RT, BINSZ - row0);   // 16, except last tile: 4

    const int*   ordBase = order + b * NPTS + c * BINSZ;
    const float* ptsB    = pts + (size_t)b * NPTS * DIM;

    // stage row points as doubles (gathered via order; cvt once per element)
    for (int f = tid; f < rowCount * (DIM / 4); f += 256) {
        int r = f >> 5;
        int q = f & 31;
        int g = ordBase[row0 + r];
        float4 v = *(const float4*)(ptsB + (size_t)g * DIM + q * 4);
        double2 d01; d01.x = (double)v.x; d01.y = (double)v.y;
        double2 d23; d23.x = (double)v.z; d23.y = (double)v.w;
        *(double2*)(&rowPd[r * RSTRD + q * 4 + 0]) = d01;
        *(double2*)(&rowPd[r * RSTRD + q * 4 + 2]) = d23;
    }
    if (tid < rowCount) {
        int g = ordBase[row0 + tid];
        ordR[tid] = g;
        naRs[tid] = na[b * NPTS + g];
    }
    __syncthreads();

    int rg = tid >> 5;   // 0..7 : rows rg, rg+8
    int cg = tid & 31;   // 0..31: cols cg, cg+32

    double naRr0 = (rg     < rowCount) ? naRs[rg]     : 0.;
    double naRr1 = (rg + 8 < rowCount) ? naRs[rg + 8] : 0.;

    // selection key: clamped squared distance (smaller = better); bottom-5,
    // strict < with in-order arrival == (key asc, idx asc), matches ref.
    double tv[2][TOPK];
    int    tl[2][TOPK];
#pragma unroll
    for (int ii = 0; ii < 2; ++ii)
#pragma unroll
        for (int k = 0; k < TOPK; ++k) { tv[ii][k] = DBL_MAX; tl[ii][k] = 0x7fffffff; }

    const int totalZ = rowCount * ROWQ;

    for (int ct = 0; ct < NCT; ++ct) {
        int col0 = ct * CTILE;
        int colCount = min(CTILE, BINSZ - col0);
        __syncthreads();   // prev tile's readers done before restage
        for (int f = tid; f < colCount * (DIM / 4); f += 256) {
            int j = f >> 5;
            int q = f & 31;
            int g = ordBase[col0 + j];
            float4 v = *(const float4*)(ptsB + (size_t)g * DIM + q * 4);
            *(float4*)(&colP[j * CSTR + q * 4]) = v;
        }
        if (tid < colCount) {
            int g = ordBase[col0 + tid];
            naC[tid] = na[b * NPTS + g];
        }
        __syncthreads();

        // zero-fill slice ct: stores drain during this tile's gram compute
        {
            float4 z = make_float4(0.f, 0.f, 0.f, 0.f);
            int z0 = (ct * totalZ) / NCT, z1 = ((ct + 1) * totalZ) / NCT;
            for (int f = z0 + tid; f < z1; f += 256) {
                int r = f / ROWQ;
                int q = f - r * ROWQ;
                float* outRow = out + ((size_t)b * NPTS + ordR[r]) * NPTS;
                *(float4*)(outRow + 4 * q) = z;
            }
        }

        double acc00 = 0., acc01 = 0., acc10 = 0., acc11 = 0.;

        for (int q = 0; q < DIM / 4; ++q) {
            double2 a0lo = *(const double2*)(&rowPd[rg * RSTRD + q * 4 + 0]);
            double2 a0hi = *(const double2*)(&rowPd[rg * RSTRD + q * 4 + 2]);
            double2 a1lo = *(const double2*)(&rowPd[(rg + 8) * RSTRD + q * 4 + 0]);
            double2 a1hi = *(const double2*)(&rowPd[(rg + 8) * RSTRD + q * 4 + 2]);
            float4 b0 = *(const float4*)(&colP[cg * CSTR + q * 4]);
            float4 b1 = *(const float4*)(&colP[(cg + 32) * CSTR + q * 4]);
            double b00 = (double)b0.x, b01 = (double)b0.y,
                   b02 = (double)b0.z, b03 = (double)b0.w;
            double b10 = (double)b1.x, b11 = (double)b1.y,
                   b12 = (double)b1.z, b13 = (double)b1.w;
            acc00 += a0lo.x * b00 + a0lo.y * b01 + a0hi.x * b02 + a0hi.y * b03;
            acc01 += a0lo.x * b10 + a0lo.y * b11 + a0hi.x * b12 + a0hi.y * b13;
            acc10 += a1lo.x * b00 + a1lo.y * b01 + a1hi.x * b02 + a1hi.y * b03;
            acc11 += a1lo.x * b10 + a1lo.y * b11 + a1hi.x * b12 + a1hi.y * b13;
        }

        // running bottom-5 (per thread, candidates arrive in increasing idx:
        // cols cg then cg+32, tiles increasing)
#pragma unroll
        for (int jj = 0; jj < 2; ++jj) {
            int j = cg + 32 * jj;
            if (j < colCount) {
                int    cl = col0 + j;
                double nc = naC[j];
                double a0 = (jj == 0) ? acc00 : acc01;
                double a1 = (jj == 0) ? acc10 : acc11;
                double cv0 = fmax(naRr0 + nc - 2. * a0, 1e-6);
                double cv1 = fmax(naRr1 + nc - 2. * a1, 1e-6);
                int cl0 = cl, cl1 = cl;
#pragma unroll
                for (int k = 0; k < TOPK; ++k) {   // strict <: equal keeps earlier idx
                    bool lt0 = (cv0 < tv[0][k]);
                    double ov0 = tv[0][k]; int ol0 = tl[0][k];
                    if (lt0) { tv[0][k] = cv0; tl[0][k] = cl0; cv0 = ov0; cl0 = ol0; }
                    bool lt1 = (cv1 < tv[1][k]);
                    double ov1 = tv[1][k]; int ol1 = tl[1][k];
                    if (lt1) { tv[1][k] = cv1; tl[1][k] = cl1; cv1 = ov1; cl1 = ol1; }
                }
            }
        }
    }

    // merge across the 32 column-threads of each row (butterfly, width 32)
#pragma unroll
    for (int m = 1; m < 32; m <<= 1) {
#pragma unroll
        for (int ii = 0; ii < 2; ++ii) {
            double rv[TOPK]; int rl[TOPK];
#pragma unroll
            for (int k = 0; k < TOPK; ++k) {
                rv[k] = __shfl_xor(tv[ii][k], m, 32);
                rl[k] = __shfl_xor(tl[ii][k], m, 32);
            }
#pragma unroll
            for (int k = 0; k < TOPK; ++k) {
                double cv = rv[k]; int cl = rl[k];
#pragma unroll
                for (int s = 0; s < TOPK; ++s) {   // (key asc, idx asc) total order
                    bool better = (cv < tv[ii][s]) || (cv == tv[ii][s] && cl < tl[ii][s]);
                    double ov = tv[ii][s]; int ol = tl[ii][s];
                    if (better) { tv[ii][s] = cv; tl[ii][s] = cl; cv = ov; cl = ol; }
                }
            }
        }
    }

    __syncthreads();   // drain last zero slice before value scatter

    // scatter: lane cg==0 of each row-group writes 2 rows x 5 values
    if (cg == 0) {
#pragma unroll
        for (int ii = 0; ii < 2; ++ii) {
            int r = rg + 8 * ii;
            if (r < rowCount) {
                int src = ordR[r];
                float* outRow = out + ((size_t)b * NPTS + src) * NPTS;
#pragma unroll
                for (int k = 0; k < TOPK; ++k) {
                    double dist = sqrt(tv[ii][k]);     // tv already clamped
                    double dm   = exp(-0.1 * dist);
                    int dst = ordBase[tl[ii][k]];      // chunk-local -> global
                    outRow[dst] = (float)dm;
                }
            }
        }
    }
}

// ---------------- launch ----------------
extern "C" void kernel_launch(void* const* d_in, const int* in_sizes, int n_in,
                              void* d_out, int out_size, void* d_ws, size_t ws_size,
                              hipStream_t stream) {
    const float* pts = (const float*)d_in[0];   // [2,5000,128]
    const float* rot = (const float*)d_in[1];   // [128,100]
    float* out = (float*)d_out;                 // [2,5000,5000]

    double* na      = (double*)d_ws;                                    // 80000 B
    int*    bin_idx = (int*)((char*)d_ws + 80000);                      // 40000 B
    int*    order   = (int*)((char*)d_ws + 120000);                     // 40000 B

    k_bins<<<(BATCH * NPTS + KB_PTS - 1) / KB_PTS, 256, 0, stream>>>(pts, rot, bin_idx, na);
    k_sort<<<BATCH, 256, 0, stream>>>(bin_idx, order);
    k_chunks<<<BATCH * NBINS * NRT, 256, 0, stream>>>(pts, na, order, out);
}